// Round 6
// baseline (888.561 us; speedup 1.0000x reference)
//
#include <hip/hip_runtime.h>
#include <math.h>

#define BB   8
#define CCH  256
#define HH   112
#define HW   12544   // 112*112
#define LDK  40      // fallback conv: padded k-stride in shorts

typedef __attribute__((ext_vector_type(8))) short  bf16x8;
typedef __attribute__((ext_vector_type(4))) short  short4v;
typedef __attribute__((ext_vector_type(4))) float  f32x4;

typedef __attribute__((address_space(1))) const void gm_cv;
typedef __attribute__((address_space(3))) void lds_v;

__device__ __forceinline__ unsigned short f2bf_rne(float f) {
    unsigned u = __float_as_uint(f);
    return (unsigned short)((u + 0x7FFFu + ((u >> 16) & 1u)) >> 16);
}
__device__ __forceinline__ float bf2f(unsigned short h) {
    return __uint_as_float(((unsigned)h) << 16);
}

// ---------------- pre-passes ----------------

// Convert 4 weight matrices [256][256] fp32 -> bf16 hi/lo (layout preserved).
__global__ __launch_bounds__(256) void w_prep(
    const float* __restrict__ w0, const float* __restrict__ w1,
    const float* __restrict__ w2, const float* __restrict__ w3,
    short* __restrict__ dst)   // 4 x (65536 hi + 65536 lo)
{
    const int which = blockIdx.y;
    const float* src = which == 0 ? w0 : which == 1 ? w1 : which == 2 ? w2 : w3;
    const int i = blockIdx.x * 256 + threadIdx.x;   // grid.x = 256 -> i < 65536
    float v = src[i];
    unsigned short hb = f2bf_rne(v);
    dst[(size_t)which * 131072 + i]         = (short)hb;
    dst[(size_t)which * 131072 + 65536 + i] = (short)f2bf_rne(v - bf2f(hb));
}

// Transpose+convert: src [b][CCH][HW] fp32 -> dhi/dlo [b][HW][CCH] bf16.
__global__ __launch_bounds__(256) void t_prep(
    const float* __restrict__ src,
    short* __restrict__ dhi, short* __restrict__ dlo)
{
    __shared__ float Ts[32][33];
    const int n0 = blockIdx.x * 32;
    const int c0 = blockIdx.y * 32;
    const int b  = blockIdx.z;
    const int tx = threadIdx.x & 31, ty = threadIdx.x >> 5;   // 32 x 8
#pragma unroll
    for (int i = 0; i < 4; ++i) {
        int c = c0 + ty + 8 * i;
        Ts[ty + 8 * i][tx] = src[((size_t)b * CCH + c) * HW + n0 + tx];
    }
    __syncthreads();
#pragma unroll
    for (int i = 0; i < 4; ++i) {
        int n = n0 + ty + 8 * i;
        float v = Ts[tx][ty + 8 * i];
        unsigned short hb = f2bf_rne(v);
        size_t o = ((size_t)b * HW + n) * CCH + c0 + tx;
        dhi[o] = (short)hb;
        dlo[o] = (short)f2bf_rne(v - bf2f(hb));
    }
}

// ---------------- main conv (m97 structure) ----------------
// Y[b][o][n] = sum_c W[o][c]*X[b][c][n]; A=W[o][c] hi/lo, B=Xt[b][n][c] hi/lo.
// 128x128 tile, BK=64, 4 waves (2x2), global_load_lds staging with XOR slot
// swizzle (slot ^= row&7, 16B slots) applied on global source + LDS read.
__global__ __launch_bounds__(256) void conv_mfma2(
    const short* __restrict__ Whi, const short* __restrict__ Wlo,
    const short* __restrict__ Xthi, const short* __restrict__ Xtlo,
    float* __restrict__ Yout, const float* __restrict__ Res)
{
    const int bm  = blockIdx.x;   // 0..1   out-channel tile (adjacent blocks share B)
    const int bn  = blockIdx.y;   // 0..97  pixel tile
    const int b   = blockIdx.z;   // 0..7
    const int tid = threadIdx.x;
    const int lane = tid & 63, wid = tid >> 6;
    const int wr = wid >> 1, wc = wid & 1;
    const int fr = lane & 15, fg = lane >> 4;

    __shared__ __align__(16) short As[2][128 * 64];  // [hi/lo][row*64 + slot*8]
    __shared__ __align__(16) short Bs[2][128 * 64];

    f32x4 acc[4][4];
#pragma unroll
    for (int m = 0; m < 4; ++m)
#pragma unroll
        for (int nf = 0; nf < 4; ++nf) acc[m][nf] = (f32x4){0.f, 0.f, 0.f, 0.f};

    // staging lane roles: 1 KiB chunk = 8 rows x 8 slots of 16 B
    const int srow  = lane >> 3;                  // row within chunk
    const int sslot = lane & 7;                   // physical slot
    const int scol  = ((sslot ^ srow) << 3);      // pre-swizzled logical col (shorts)

    const size_t xbase = ((size_t)b * HW + (size_t)bn * 128) * CCH;

    for (int k0 = 0; k0 < CCH; k0 += 64) {
#pragma unroll
        for (int j = 0; j < 4; ++j) {
            const int ch  = wid * 4 + j;          // chunk 0..15
            const int row = ch * 8 + srow;        // 0..127
            const size_t wo = (size_t)(bm * 128 + row) * CCH + k0 + scol;
            const size_t xo = xbase + (size_t)row * CCH + k0 + scol;
            __builtin_amdgcn_global_load_lds((gm_cv*)(Whi + wo),  (lds_v*)&As[0][ch * 512], 16, 0, 0);
            __builtin_amdgcn_global_load_lds((gm_cv*)(Wlo + wo),  (lds_v*)&As[1][ch * 512], 16, 0, 0);
            __builtin_amdgcn_global_load_lds((gm_cv*)(Xthi + xo), (lds_v*)&Bs[0][ch * 512], 16, 0, 0);
            __builtin_amdgcn_global_load_lds((gm_cv*)(Xtlo + xo), (lds_v*)&Bs[1][ch * 512], 16, 0, 0);
        }
        __syncthreads();   // drains vmcnt

#pragma unroll
        for (int s = 0; s < 2; ++s) {
            bf16x8 ah[4], al[4], bh[4], bl[4];
#pragma unroll
            for (int m = 0; m < 4; ++m) {
                const int row = wr * 64 + m * 16 + fr;
                const int off = row * 64 + ((((s * 4 + fg) ^ (fr & 7))) << 3);
                ah[m] = *(const bf16x8*)&As[0][off];
                al[m] = *(const bf16x8*)&As[1][off];
            }
#pragma unroll
            for (int nf = 0; nf < 4; ++nf) {
                const int row = wc * 64 + nf * 16 + fr;
                const int off = row * 64 + ((((s * 4 + fg) ^ (fr & 7))) << 3);
                bh[nf] = *(const bf16x8*)&Bs[0][off];
                bl[nf] = *(const bf16x8*)&Bs[1][off];
            }
#pragma unroll
            for (int m = 0; m < 4; ++m)
#pragma unroll
                for (int nf = 0; nf < 4; ++nf) {
                    acc[m][nf] = __builtin_amdgcn_mfma_f32_16x16x32_bf16(ah[m], bh[nf], acc[m][nf], 0, 0, 0);
                    acc[m][nf] = __builtin_amdgcn_mfma_f32_16x16x32_bf16(ah[m], bl[nf], acc[m][nf], 0, 0, 0);
                    acc[m][nf] = __builtin_amdgcn_mfma_f32_16x16x32_bf16(al[m], bh[nf], acc[m][nf], 0, 0, 0);
                }
        }
        __syncthreads();
    }

    // epilogue: C/D layout col=lane&15, row=(lane>>4)*4+reg  (verified r5)
#pragma unroll
    for (int m = 0; m < 4; ++m)
#pragma unroll
        for (int nf = 0; nf < 4; ++nf) {
            const int gcol = bn * 128 + wc * 64 + nf * 16 + fr;
#pragma unroll
            for (int q = 0; q < 4; ++q) {
                const int grow = bm * 128 + wr * 64 + m * 16 + fg * 4 + q;
                const size_t idx = ((size_t)b * CCH + grow) * HW + gcol;
                float v = acc[m][nf][q];
                if (Res) v = fmaxf(v + Res[idx], 0.f);
                Yout[idx] = v;
            }
        }
}

// ---------------- fallback conv (round-5, proven) ----------------
__global__ __launch_bounds__(256) void conv_mfma(
    const float* __restrict__ Wm,
    const float* __restrict__ Xin,
    float* __restrict__ Yout,
    const float* __restrict__ Res)
{
    const int bn  = blockIdx.x;
    const int bm  = blockIdx.y;
    const int b   = blockIdx.z;
    const int tid = threadIdx.x;

    __shared__ __align__(16) short As[2][128 * LDK];
    __shared__ __align__(16) short Bs[2][128 * LDK];

    const float* Xb = Xin + (size_t)b * CCH * HW;

    f32x4 acc[4][4];
#pragma unroll
    for (int m = 0; m < 4; ++m)
#pragma unroll
        for (int nf = 0; nf < 4; ++nf) acc[m][nf] = (f32x4){0.f, 0.f, 0.f, 0.f};

    const int ao  = tid >> 1;
    const int akh = (tid & 1) << 4;
    const int bnp = tid & 31;
    const int bcp = tid >> 5;

    const int lane = tid & 63;
    const int wid  = tid >> 6;
    const int wr = wid >> 1, wc = wid & 1;
    const int fr = lane & 15;
    const int fg = lane >> 4;

    for (int k0 = 0; k0 < CCH; k0 += 32) {
        {
            const float* wsrc = Wm + (size_t)(bm * 128 + ao) * CCH + k0 + akh;
            float4 w0 = *(const float4*)(wsrc + 0);
            float4 w1 = *(const float4*)(wsrc + 4);
            float4 w2 = *(const float4*)(wsrc + 8);
            float4 w3 = *(const float4*)(wsrc + 12);
            float wf[16] = {w0.x, w0.y, w0.z, w0.w, w1.x, w1.y, w1.z, w1.w,
                            w2.x, w2.y, w2.z, w2.w, w3.x, w3.y, w3.z, w3.w};
            bf16x8 h0, h1, l0, l1;
#pragma unroll
            for (int i = 0; i < 8; ++i) {
                unsigned short hb = f2bf_rne(wf[i]);
                h0[i] = (short)hb;
                l0[i] = (short)f2bf_rne(wf[i] - bf2f(hb));
            }
#pragma unroll
            for (int i = 0; i < 8; ++i) {
                unsigned short hb = f2bf_rne(wf[8 + i]);
                h1[i] = (short)hb;
                l1[i] = (short)f2bf_rne(wf[8 + i] - bf2f(hb));
            }
            *(bf16x8*)&As[0][ao * LDK + akh]     = h0;
            *(bf16x8*)&As[0][ao * LDK + akh + 8] = h1;
            *(bf16x8*)&As[1][ao * LDK + akh]     = l0;
            *(bf16x8*)&As[1][ao * LDK + akh + 8] = l1;
        }
        {
            const float* xsrc = Xb + (size_t)(k0 + bcp * 4) * HW + (size_t)bn * 128 + bnp * 4;
            float4 r0 = *(const float4*)(xsrc);
            float4 r1 = *(const float4*)(xsrc + HW);
            float4 r2 = *(const float4*)(xsrc + 2 * HW);
            float4 r3 = *(const float4*)(xsrc + 3 * HW);
            float rf[4][4] = {{r0.x, r0.y, r0.z, r0.w},
                              {r1.x, r1.y, r1.z, r1.w},
                              {r2.x, r2.y, r2.z, r2.w},
                              {r3.x, r3.y, r3.z, r3.w}};
#pragma unroll
            for (int j = 0; j < 4; ++j) {
                short4v hv, lv;
#pragma unroll
                for (int rr = 0; rr < 4; ++rr) {
                    unsigned short hb = f2bf_rne(rf[rr][j]);
                    hv[rr] = (short)hb;
                    lv[rr] = (short)f2bf_rne(rf[rr][j] - bf2f(hb));
                }
                *(short4v*)&Bs[0][(bnp * 4 + j) * LDK + bcp * 4] = hv;
                *(short4v*)&Bs[1][(bnp * 4 + j) * LDK + bcp * 4] = lv;
            }
        }
        __syncthreads();

        bf16x8 ah[4], al[4], bh[4], bl[4];
#pragma unroll
        for (int m = 0; m < 4; ++m) {
            const int off = (wr * 64 + m * 16 + fr) * LDK + fg * 8;
            ah[m] = *(const bf16x8*)&As[0][off];
            al[m] = *(const bf16x8*)&As[1][off];
        }
#pragma unroll
        for (int nf = 0; nf < 4; ++nf) {
            const int off = (wc * 64 + nf * 16 + fr) * LDK + fg * 8;
            bh[nf] = *(const bf16x8*)&Bs[0][off];
            bl[nf] = *(const bf16x8*)&Bs[1][off];
        }
#pragma unroll
        for (int m = 0; m < 4; ++m)
#pragma unroll
            for (int nf = 0; nf < 4; ++nf) {
                acc[m][nf] = __builtin_amdgcn_mfma_f32_16x16x32_bf16(ah[m], bh[nf], acc[m][nf], 0, 0, 0);
                acc[m][nf] = __builtin_amdgcn_mfma_f32_16x16x32_bf16(ah[m], bl[nf], acc[m][nf], 0, 0, 0);
                acc[m][nf] = __builtin_amdgcn_mfma_f32_16x16x32_bf16(al[m], bh[nf], acc[m][nf], 0, 0, 0);
            }
        __syncthreads();
    }

#pragma unroll
    for (int m = 0; m < 4; ++m)
#pragma unroll
        for (int nf = 0; nf < 4; ++nf) {
            const int gcol = bn * 128 + wc * 64 + nf * 16 + fr;
#pragma unroll
            for (int q = 0; q < 4; ++q) {
                const int grow = bm * 128 + wr * 64 + m * 16 + fg * 4 + q;
                const size_t idx = ((size_t)b * CCH + grow) * HW + gcol;
                float v = acc[m][nf][q];
                if (Res) v = fmaxf(v + Res[idx], 0.f);
                Yout[idx] = v;
            }
        }
}

// ---------------- attention (512 threads: 2 waves/SIMD) ----------------
// One block per (b,c). ty<28 compute 4 rows x 7 cols each; wave 7 stages+idles.
__global__ __launch_bounds__(512) void attn_kernel(
    const float* __restrict__ Qg,
    const float* __restrict__ Kg,
    const float* __restrict__ Vg,
    float* __restrict__ Zg)
{
    const int bc  = blockIdx.x;    // 0..2047
    const int tid = threadIdx.x;
    const int tx  = tid & 15;
    const int ty  = tid >> 4;      // 0..31

    __shared__ float Qs[HH][116];  // later reused to hold M
    __shared__ float Ks[HH][116];
    __shared__ float Vs[HH][116];

    const float* Qp = Qg + (size_t)bc * HW;
    const float* Kp = Kg + (size_t)bc * HW;
    const float* Vp = Vg + (size_t)bc * HW;

    for (int idx = tid; idx < HW / 4; idx += 512) {
        int row = idx / 28;
        int c4  = (idx % 28) * 4;
        *(float4*)&Qs[row][c4] = *(const float4*)(Qp + row * HH + c4);
        *(float4*)&Ks[row][c4] = *(const float4*)(Kp + row * HH + c4);
        *(float4*)&Vs[row][c4] = *(const float4*)(Vp + row * HH + c4);
    }
    __syncthreads();

    const bool act = (ty < 28);
    const int i0 = ty * 4;   // 4 rows per active thread
    const int j0 = tx * 7;   // 7 cols per thread

    float s[4][7];
    if (act) {
#pragma unroll
        for (int ii = 0; ii < 4; ++ii)
#pragma unroll
            for (int jj = 0; jj < 7; ++jj) s[ii][jj] = 0.f;

        for (int k = 0; k < HH; ++k) {
            float qv[4], kv[7];
#pragma unroll
            for (int ii = 0; ii < 4; ++ii) qv[ii] = Qs[i0 + ii][k];
#pragma unroll
            for (int jj = 0; jj < 7; ++jj) kv[jj] = Ks[k][j0 + jj];
#pragma unroll
            for (int ii = 0; ii < 4; ++ii)
#pragma unroll
                for (int jj = 0; jj < 7; ++jj)
                    s[ii][jj] = fmaf(qv[ii], kv[jj], s[ii][jj]);
        }

#pragma unroll
        for (int ii = 0; ii < 4; ++ii) {
            float mx = s[ii][0];
#pragma unroll
            for (int jj = 1; jj < 7; ++jj) mx = fmaxf(mx, s[ii][jj]);
#pragma unroll
            for (int off = 1; off < 16; off <<= 1) mx = fmaxf(mx, __shfl_xor(mx, off));
            float sum = 0.f;
#pragma unroll
            for (int jj = 0; jj < 7; ++jj) {
                float e = __expf(s[ii][jj] - mx);
                s[ii][jj] = e;
                sum += e;
            }
#pragma unroll
            for (int off = 1; off < 16; off <<= 1) sum += __shfl_xor(sum, off);
            float inv = 1.0f / sum;
#pragma unroll
            for (int jj = 0; jj < 7; ++jj) s[ii][jj] *= inv;
        }
    }

    __syncthreads();   // all reads of Qs (Q) complete
    if (act) {
#pragma unroll
        for (int ii = 0; ii < 4; ++ii)
#pragma unroll
            for (int jj = 0; jj < 7; ++jj)
                Qs[i0 + ii][j0 + jj] = s[ii][jj];   // M overwrites Q
    }
    __syncthreads();

    if (act) {
        float z[4][7];
#pragma unroll
        for (int ii = 0; ii < 4; ++ii)
#pragma unroll
            for (int ww = 0; ww < 7; ++ww) z[ii][ww] = 0.f;

        for (int j = 0; j < HH; ++j) {
            float mv[4], vv[7];
#pragma unroll
            for (int ii = 0; ii < 4; ++ii) mv[ii] = Qs[i0 + ii][j];
#pragma unroll
            for (int ww = 0; ww < 7; ++ww) vv[ww] = Vs[j][j0 + ww];
#pragma unroll
            for (int ii = 0; ii < 4; ++ii)
#pragma unroll
                for (int ww = 0; ww < 7; ++ww)
                    z[ii][ww] = fmaf(mv[ii], vv[ww], z[ii][ww]);
        }

        float* Zp = Zg + (size_t)bc * HW;
#pragma unroll
        for (int ii = 0; ii < 4; ++ii)
#pragma unroll
            for (int ww = 0; ww < 7; ++ww)
                Zp[(i0 + ii) * HH + j0 + ww] = z[ii][ww];
    }
}

extern "C" void kernel_launch(void* const* d_in, const int* in_sizes, int n_in,
                              void* d_out, int out_size, void* d_ws, size_t ws_size,
                              hipStream_t stream) {
    const float* x  = (const float*)d_in[0];
    const float* y  = (const float*)d_in[1];
    const float* WQ = (const float*)d_in[2];
    const float* WK = (const float*)d_in[3];
    const float* WV = (const float*)d_in[4];
    const float* WZ = (const float*)d_in[5];
    float* out = (float*)d_out;

    const size_t n = (size_t)BB * CCH * HW;        // 25,690,112 elements
    const size_t S_BYTES = n * 4;                  // 102,760,448 B (fp32 tensor == bf16 hi+lo pair)
    const size_t NEED = 3 * S_BYTES + (size_t)4 * CCH * CCH * 2 * sizeof(short);

    if (ws_size >= NEED) {
        // slotA: transposed bf16 hi/lo (Xt -> Yt -> Zt). slotB: K fp32 (then Z).
        // slotC: V fp32. wbuf: 4 weights bf16 hi/lo. Q lives in d_out.
        short* At_hi = (short*)d_ws;
        short* At_lo = At_hi + n;
        float* Kb = (float*)((char*)d_ws + S_BYTES);
        float* Vb = (float*)((char*)d_ws + 2 * S_BYTES);
        short* Wb = (short*)((char*)d_ws + 3 * S_BYTES);
        float* Qb = out;
        float* Zb = Kb;

        dim3 tgrid(HW / 32, CCH / 32, BB);
        dim3 cgrid(2, 98, 8);

        w_prep<<<dim3(256, 4), 256, 0, stream>>>(WQ, WK, WV, WZ, Wb);
        t_prep<<<tgrid, 256, 0, stream>>>(x, At_hi, At_lo);
        conv_mfma2<<<cgrid, 256, 0, stream>>>(Wb, Wb + 65536, At_hi, At_lo, Qb, nullptr);
        t_prep<<<tgrid, 256, 0, stream>>>(y, At_hi, At_lo);
        conv_mfma2<<<cgrid, 256, 0, stream>>>(Wb + 131072, Wb + 131072 + 65536, At_hi, At_lo, Kb, nullptr);
        conv_mfma2<<<cgrid, 256, 0, stream>>>(Wb + 262144, Wb + 262144 + 65536, At_hi, At_lo, Vb, nullptr);
        attn_kernel<<<dim3(2048), 512, 0, stream>>>(Qb, Kb, Vb, Zb);
        t_prep<<<tgrid, 256, 0, stream>>>(Zb, At_hi, At_lo);
        conv_mfma2<<<cgrid, 256, 0, stream>>>(Wb + 393216, Wb + 393216 + 65536, At_hi, At_lo, out, x);
    } else {
        // fallback: round-5 proven path (needs 2*S_BYTES)
        float* Kb = (float*)d_ws;
        float* Vb = Kb + n;
        float* Zb = Kb;
        float* Qb = out;
        dim3 grid(98, 2, 8);
        conv_mfma<<<grid, 256, 0, stream>>>(WQ, x, Qb, nullptr);
        conv_mfma<<<grid, 256, 0, stream>>>(WK, y, Kb, nullptr);
        conv_mfma<<<grid, 256, 0, stream>>>(WV, y, Vb, nullptr);
        attn_kernel<<<dim3(2048), 512, 0, stream>>>(Qb, Kb, Vb, Zb);
        conv_mfma<<<grid, 256, 0, stream>>>(WZ, Zb, out, x);
    }
}